// Round 2
// baseline (525.609 us; speedup 1.0000x reference)
//
#include <hip/hip_runtime.h>

// GRU, B=16384 rows, T=4096 steps, H=1, fp32. One thread per row; 256 waves
// over 256 CUs. Pure dependency-latency-bound: wall = 4096 * path_cycles.
// Path minimized to exp2 -> add -> rcp -> fma -> exp2 -> add -> rcp -> fma
// (16 + 4*L_trans cycles) by folding h'/uR_next algebra into one fma off the
// critical path:  u' = c1*q + c0,  c1 = 2*Ar*(z-1),  c0 = Ar*(z*(h-1)+1)+Cr'.

#define LOG2E 1.4426950408889634f
#define T_LEN 4096
#define B_ROWS 16384

__device__ __forceinline__ float fast_exp2(float x) {
    return __builtin_amdgcn_exp2f(x);
}
__device__ __forceinline__ float fast_rcp(float x) {
    return __builtin_amdgcn_rcpf(x);
}

// One GRU step. Carries (h, u) where u = -log2e * a_r (so r = 1/(1+exp2(u))).
// xc = x_t (for z and n projections), xn = x_{t+1} (for next step's r proj).
#define GRU_STEP(h, u, xc, xn)                                              \
    do {                                                                    \
        /* ---- critical path: eR -> P -> r -> v -> e2 -> S -> q -> u' ---- */ \
        float eR = fast_exp2(u);                                            \
        /* off-path (needs only h, x): z-gate, n coefficients */            \
        float uZ  = __builtin_fmaf((h), Az, __builtin_fmaf((xc), az1, az0));\
        float eZ  = fast_exp2(uZ);                                          \
        float z   = fast_rcp(1.0f + eZ);                                    \
        float Gn  = __builtin_fmaf((h), An, Bn);                            \
        float Cn  = __builtin_fmaf((xc), an1, an0);                         \
        float hm1 = (h) - 1.0f;                                             \
        float Crn = __builtin_fmaf((xn), ar1, ar0);                         \
        /* path */                                                          \
        float P  = 1.0f + eR;                                               \
        float r  = fast_rcp(P);                                             \
        float v  = __builtin_fmaf(r, Gn, Cn);                               \
        float e2 = fast_exp2(v);                                            \
        float S  = 1.0f + e2;                                               \
        float q  = fast_rcp(S);                                             \
        /* off-path once z ready */                                         \
        float c1 = __builtin_fmaf(TwoAr, z, mTwoAr);                        \
        float w0 = __builtin_fmaf(z, hm1, 1.0f);                            \
        float c0 = __builtin_fmaf(Ar, w0, Crn);                             \
        /* path: next r-gate argument directly from q */                    \
        (u) = __builtin_fmaf(c1, q, c0);                                    \
        /* off-path: materialize h' for next step's off-path work */        \
        float t1 = __builtin_fmaf(2.0f, q, hm1);                            \
        float nn = __builtin_fmaf(-2.0f, q, 1.0f);                          \
        (h) = __builtin_fmaf(z, t1, nn);                                    \
    } while (0)

__global__ __launch_bounds__(64, 1)
void gru_scan_kernel(const float* __restrict__ x,
                     const float* __restrict__ w_ih,
                     const float* __restrict__ w_hh,
                     const float* __restrict__ b_ih,
                     const float* __restrict__ b_hh,
                     const float* __restrict__ fc_w,
                     const float* __restrict__ fc_b,
                     float* __restrict__ out)
{
    const int row = blockIdx.x * 64 + threadIdx.x;

    // Wave-uniform weight scalars (gate order: r, z, n).
    const float wr = w_ih[0], wz = w_ih[1], wn = w_ih[2];
    const float vr = w_hh[0], vz = w_hh[1], vn = w_hh[2];
    const float br = b_ih[0], bz = b_ih[1], bn = b_ih[2];
    const float cr = b_hh[0], cz = b_hh[1], cn = b_hh[2];

    const float ar1 = -LOG2E * wr, ar0 = -LOG2E * (br + cr), Ar = -LOG2E * vr;
    const float az1 = -LOG2E * wz, az0 = -LOG2E * (bz + cz), Az = -LOG2E * vz;
    const float an1 = 2.0f * LOG2E * wn, an0 = 2.0f * LOG2E * bn;
    const float An  = 2.0f * LOG2E * vn, Bn  = 2.0f * LOG2E * cn;
    const float TwoAr = 2.0f * Ar, mTwoAr = -2.0f * Ar;

    const float fcw = fc_w[0], fcb = fc_b[0];

    const float4* xr = (const float4*)(x + (size_t)row * T_LEN);

    // Register double-buffer: tiles of 32 timesteps (8 x float4).
    float4 A[8], Bv[8];
#pragma unroll
    for (int k = 0; k < 8; ++k) A[k] = xr[k];

    float h = 0.0f;
    // u_0 = Cr_0 (h0 = 0)
    float u = __builtin_fmaf(A[0].x, ar1, ar0);

    // Process one 8-float4 tile; xnext0 = first x of the following tile.
#define TILE(BUF, OTHER)                                                    \
    do {                                                                    \
        _Pragma("unroll")                                                   \
        for (int k = 0; k < 8; ++k) {                                       \
            float4 xv = BUF[k];                                             \
            float xnx = (k < 7) ? BUF[k + 1].x : OTHER[0].x;                \
            GRU_STEP(h, u, xv.x, xv.y);                                     \
            GRU_STEP(h, u, xv.y, xv.z);                                     \
            GRU_STEP(h, u, xv.z, xv.w);                                     \
            GRU_STEP(h, u, xv.w, xnx);                                      \
        }                                                                   \
    } while (0)

#pragma unroll 1
    for (int tb = 0; tb < 128; tb += 2) {
        // Prefetch tile tb+1 into Bv while computing tile tb from A.
        const float4* pB = xr + (tb + 1) * 8;
#pragma unroll
        for (int k = 0; k < 8; ++k) Bv[k] = pB[k];

        TILE(A, Bv);

        // Prefetch tile tb+2 into A (wraps to tile 0 on the last pair:
        // in-bounds re-read; the chained u' from the final step is unused).
        const float4* pA = xr + ((tb + 2) & 127) * 8;
#pragma unroll
        for (int k = 0; k < 8; ++k) A[k] = pA[k];

        TILE(Bv, A);
    }

    out[row] = __builtin_fmaf(h, fcw, fcb);
}

extern "C" void kernel_launch(void* const* d_in, const int* in_sizes, int n_in,
                              void* d_out, int out_size, void* d_ws, size_t ws_size,
                              hipStream_t stream)
{
    const float* x    = (const float*)d_in[0];
    const float* w_ih = (const float*)d_in[1];
    const float* w_hh = (const float*)d_in[2];
    const float* b_ih = (const float*)d_in[3];
    const float* b_hh = (const float*)d_in[4];
    const float* fc_w = (const float*)d_in[5];
    const float* fc_b = (const float*)d_in[6];
    float* out = (float*)d_out;

    gru_scan_kernel<<<B_ROWS / 64, 64, 0, stream>>>(
        x, w_ih, w_hh, b_ih, b_hh, fc_w, fc_b, out);
}